// Round 2
// baseline (82.086 us; speedup 1.0000x reference)
//
#include <hip/hip_runtime.h>
#include <hip/hip_bf16.h>

#define LQ 256
#define NB 4
#define MM 1024   // NB*LQ
#define DH 256
#define CCONST 5.0f

__device__ __forceinline__ float bf2f(unsigned short u) {
    union { unsigned int i; float f; } v; v.i = ((unsigned int)u) << 16; return v.f;
}
__device__ __forceinline__ unsigned short f2bf(float f) {
    union { float f; unsigned int i; } v; v.f = f;
    unsigned int x = v.i;
    return (unsigned short)((x + 0x7fffu + ((x >> 16) & 1u)) >> 16);
}
// dtype-flexible loads: isbf=1 -> bf16 ushorts, isbf=0 -> float32
__device__ __forceinline__ float ldin(const void* p, int idx, int isbf) {
    return isbf ? bf2f(((const unsigned short*)p)[idx]) : ((const float*)p)[idx];
}
__device__ __forceinline__ void ld4(const void* p, int idx, int isbf, float o[4]) {
    if (isbf) {
        ushort4 u = *(const ushort4*)((const unsigned short*)p + idx);
        o[0] = bf2f(u.x); o[1] = bf2f(u.y); o[2] = bf2f(u.z); o[3] = bf2f(u.w);
    } else {
        float4 f = *(const float4*)((const float*)p + idx);
        o[0] = f.x; o[1] = f.y; o[2] = f.z; o[3] = f.w;
    }
}

// -------- dtype detect: f32 data read as ushorts has ~22% insane bf16 exponents --------
__global__ void k_detect(const unsigned short* __restrict__ x,
                         const unsigned short* __restrict__ w, int* __restrict__ flag) {
    __shared__ int cnt;
    if (threadIdx.x == 0) cnt = 0;
    __syncthreads();
    int c = 0;
    for (int i = threadIdx.x; i < 512; i += 64) {
        unsigned e1 = (x[i] >> 7) & 0xFFu;
        unsigned e2 = (w[i] >> 7) & 0xFFu;
        c += (e1 >= 0xC8u) + (e2 >= 0xC8u);
    }
    atomicAdd(&cnt, c);
    __syncthreads();
    if (threadIdx.x == 0) *flag = (cnt < 8) ? 1 : 0;
}

// ---------------- Kernel A: rep = elu(X @ Wfc^T + b), also write rep_t ----------------
__global__ __launch_bounds__(256) void k_fc(
    const void* __restrict__ X, const void* __restrict__ W, const void* __restrict__ bias,
    const int* __restrict__ flag, float* __restrict__ rep, float* __restrict__ rep_t)
{
    const int isbf = *flag;
    __shared__ float As[32][33];
    __shared__ float Ws[32][33];
    const int tid = threadIdx.x;
    const int bx = blockIdx.x, by = blockIdx.y;
    const int row0 = by * 32, col0 = bx * 32;
    const int lr = tid >> 3, k4 = (tid & 7) * 4;
    const int ty = tid >> 4, tx = tid & 15;
    float a00 = 0.f, a01 = 0.f, a10 = 0.f, a11 = 0.f;
    for (int kk = 0; kk < DH; kk += 32) {
        float xa[4], wa[4];
        ld4(X, (row0 + lr) * DH + kk + k4, isbf, xa);
        ld4(W, (col0 + lr) * DH + kk + k4, isbf, wa);
        __syncthreads();
        As[lr][k4 + 0] = xa[0]; As[lr][k4 + 1] = xa[1]; As[lr][k4 + 2] = xa[2]; As[lr][k4 + 3] = xa[3];
        Ws[lr][k4 + 0] = wa[0]; Ws[lr][k4 + 1] = wa[1]; Ws[lr][k4 + 2] = wa[2]; Ws[lr][k4 + 3] = wa[3];
        __syncthreads();
        #pragma unroll
        for (int k = 0; k < 32; ++k) {
            float x0 = As[ty * 2][k], x1 = As[ty * 2 + 1][k];
            float w0 = Ws[tx * 2][k], w1v = Ws[tx * 2 + 1][k];
            a00 += x0 * w0; a01 += x0 * w1v; a10 += x1 * w0; a11 += x1 * w1v;
        }
    }
    float accs[2][2] = {{a00, a01}, {a10, a11}};
    #pragma unroll
    for (int dr = 0; dr < 2; ++dr)
        #pragma unroll
        for (int dc = 0; dc < 2; ++dc) {
            int r = row0 + ty * 2 + dr, c = col0 + tx * 2 + dc;
            float v = accs[dr][dc] + ldin(bias, c, isbf);
            v = (v > 0.f) ? v : (__expf(v) - 1.f);
            rep[r * DH + c] = v;
            rep_t[((r & 0xFFFFFF00) + c) * LQ + (r & 255)] = v;
        }
}

// ---------------- Kernel B: dep_t = (rep @ W1^T + b1)^T, head_t = (rep @ W2^T)^T ------
__global__ __launch_bounds__(256) void k_dephead(
    const float* __restrict__ rep, const void* __restrict__ W1, const void* __restrict__ W2,
    const void* __restrict__ b1, const int* __restrict__ flag,
    float* __restrict__ dep_t, float* __restrict__ head_t)
{
    const int isbf = *flag;
    __shared__ float As[32][33];
    __shared__ float W1s[32][33];
    __shared__ float W2s[32][33];
    const int tid = threadIdx.x;
    const int bx = blockIdx.x, by = blockIdx.y;
    const int row0 = by * 32, col0 = bx * 32;
    const int lr = tid >> 3, k4 = (tid & 7) * 4;
    const int ty = tid >> 4, tx = tid & 15;
    float d00 = 0.f, d01 = 0.f, d10 = 0.f, d11 = 0.f;
    float h00 = 0.f, h01 = 0.f, h10 = 0.f, h11 = 0.f;
    for (int kk = 0; kk < DH; kk += 32) {
        float4 xa = *(const float4*)(rep + (row0 + lr) * DH + kk + k4);
        float w1a[4], w2a[4];
        ld4(W1, (col0 + lr) * DH + kk + k4, isbf, w1a);
        ld4(W2, (col0 + lr) * DH + kk + k4, isbf, w2a);
        __syncthreads();
        As[lr][k4 + 0] = xa.x; As[lr][k4 + 1] = xa.y; As[lr][k4 + 2] = xa.z; As[lr][k4 + 3] = xa.w;
        W1s[lr][k4 + 0] = w1a[0]; W1s[lr][k4 + 1] = w1a[1]; W1s[lr][k4 + 2] = w1a[2]; W1s[lr][k4 + 3] = w1a[3];
        W2s[lr][k4 + 0] = w2a[0]; W2s[lr][k4 + 1] = w2a[1]; W2s[lr][k4 + 2] = w2a[2]; W2s[lr][k4 + 3] = w2a[3];
        __syncthreads();
        #pragma unroll
        for (int k = 0; k < 32; ++k) {
            float x0 = As[ty * 2][k], x1 = As[ty * 2 + 1][k];
            float u0 = W1s[tx * 2][k], u1 = W1s[tx * 2 + 1][k];
            float v0 = W2s[tx * 2][k], v1 = W2s[tx * 2 + 1][k];
            d00 += x0 * u0; d01 += x0 * u1; d10 += x1 * u0; d11 += x1 * u1;
            h00 += x0 * v0; h01 += x0 * v1; h10 += x1 * v0; h11 += x1 * v1;
        }
    }
    float daccs[2][2] = {{d00, d01}, {d10, d11}};
    float haccs[2][2] = {{h00, h01}, {h10, h11}};
    #pragma unroll
    for (int dr = 0; dr < 2; ++dr)
        #pragma unroll
        for (int dc = 0; dc < 2; ++dc) {
            int r = row0 + ty * 2 + dr, c = col0 + tx * 2 + dc;
            int tix = ((r & 0xFFFFFF00) + c) * LQ + (r & 255);
            dep_t[tix] = daccs[dr][dc] + ldin(b1, c, isbf);
            head_t[tix] = haccs[dr][dc];
        }
}

// ---------------- Kernel C: per-(b,h) masked channel-softmax attention ----------------
__global__ __launch_bounds__(256) void k_attn(
    const float* __restrict__ dep_t, const float* __restrict__ head_t,
    const float* __restrict__ rep_t, float* __restrict__ attn_t)
{
    __shared__ float depL[256];
    __shared__ float repL[256];
    __shared__ float sufm[256];
    const int i = threadIdx.x;
    const int bh = blockIdx.x;      // b*256 + h
    const float depv = dep_t[bh * LQ + i];
    const float repv = rep_t[bh * LQ + i];
    const float headv = head_t[bh * LQ + i];
    depL[i] = depv; repL[i] = repv; sufm[i] = depv;
    __syncthreads();
    // suffix max (inclusive): sufm[i] = max(dep[i..255])
    #pragma unroll
    for (int off = 1; off < 256; off <<= 1) {
        float o = (i + off < 256) ? sufm[i + off] : -1e30f;
        float vv = sufm[i];
        __syncthreads();
        sufm[i] = fmaxf(vv, o);
        __syncthreads();
    }
    const float invC = 1.0f / CCONST;
    float m = 0.f;
    if (i < 255) {
        // max_j>i logits = C*tanh((max_j>i dep[j] + head)/C)  (tanh monotone)
        float y = (sufm[i + 1] + headv) * invC;
        float e2 = __expf(y + y);
        float t = 1.f - 2.f / (e2 + 1.f);
        m = fmaxf(0.f, CCONST * t);
    }
    float s = 0.f, acc = 0.f;
    for (int j = i + 1; j < LQ; ++j) {
        float y = (depL[j] + headv) * invC;
        float e2 = __expf(y + y);
        float t = 1.f - 2.f * __builtin_amdgcn_rcpf(e2 + 1.f);
        float e = __expf(CCONST * t - m);
        s += e;
        acc += e * repL[j];
    }
    attn_t[bh * LQ + i] = (s > 0.f) ? (acc / (s + 1e-20f)) : 0.f;
}

// ---------------- Kernel D: gate = sigmoid(rep@Wf1^T + attn@Wf2^T + bf); blend -------
__global__ __launch_bounds__(256) void k_fuse(
    const float* __restrict__ rep, const float* __restrict__ attn_t,
    const void* __restrict__ Wf1, const void* __restrict__ Wf2,
    const void* __restrict__ bfb, const void* __restrict__ rmask,
    const int* __restrict__ flag, void* __restrict__ out)
{
    const int isbf = *flag;
    __shared__ float A1[32][33];
    __shared__ float A2[32][33];
    __shared__ float W1s[32][33];
    __shared__ float W2s[32][33];
    const int tid = threadIdx.x;
    const int bx = blockIdx.x, by = blockIdx.y;
    const int row0 = by * 32, col0 = bx * 32;
    const int bb = row0 >> 8, i0 = row0 & 255;
    const int lr = tid >> 3, k4 = (tid & 7) * 4;
    const int ty = tid >> 4, tx = tid & 15;
    float a00 = 0.f, a01 = 0.f, a10 = 0.f, a11 = 0.f;
    for (int kk = 0; kk < DH; kk += 32) {
        float4 x1 = *(const float4*)(rep + (row0 + lr) * DH + kk + k4);
        // A2[l_local][k_local] = attn_t[bb][h=kk+k_local][l=i0+l_local]
        float4 x2 = *(const float4*)(attn_t + (bb * 256 + kk + lr) * LQ + i0 + k4);
        float w1a[4], w2a[4];
        ld4(Wf1, (col0 + lr) * DH + kk + k4, isbf, w1a);
        ld4(Wf2, (col0 + lr) * DH + kk + k4, isbf, w2a);
        __syncthreads();
        A1[lr][k4 + 0] = x1.x; A1[lr][k4 + 1] = x1.y; A1[lr][k4 + 2] = x1.z; A1[lr][k4 + 3] = x1.w;
        A2[k4 + 0][lr] = x2.x; A2[k4 + 1][lr] = x2.y; A2[k4 + 2][lr] = x2.z; A2[k4 + 3][lr] = x2.w;
        W1s[lr][k4 + 0] = w1a[0]; W1s[lr][k4 + 1] = w1a[1]; W1s[lr][k4 + 2] = w1a[2]; W1s[lr][k4 + 3] = w1a[3];
        W2s[lr][k4 + 0] = w2a[0]; W2s[lr][k4 + 1] = w2a[1]; W2s[lr][k4 + 2] = w2a[2]; W2s[lr][k4 + 3] = w2a[3];
        __syncthreads();
        #pragma unroll
        for (int k = 0; k < 32; ++k) {
            float r0 = A1[ty * 2][k], r1 = A1[ty * 2 + 1][k];
            float t0 = A2[ty * 2][k], t1 = A2[ty * 2 + 1][k];
            float u0 = W1s[tx * 2][k], u1 = W1s[tx * 2 + 1][k];
            float v0 = W2s[tx * 2][k], v1 = W2s[tx * 2 + 1][k];
            a00 += r0 * u0 + t0 * v0; a01 += r0 * u1 + t0 * v1;
            a10 += r1 * u0 + t1 * v0; a11 += r1 * u1 + t1 * v1;
        }
    }
    float accs[2][2] = {{a00, a01}, {a10, a11}};
    #pragma unroll
    for (int dr = 0; dr < 2; ++dr)
        #pragma unroll
        for (int dc = 0; dc < 2; ++dc) {
            int r = row0 + ty * 2 + dr, c = col0 + tx * 2 + dc;
            float z = accs[dr][dc] + ldin(bfb, c, isbf);
            float g = 1.f / (1.f + __expf(-z));
            float rv = rep[r * DH + c];
            float av = attn_t[((r & 0xFFFFFF00) + c) * LQ + (r & 255)];
            float o = (g * rv + (1.f - g) * av) * ldin(rmask, r, isbf);
            if (isbf) ((unsigned short*)out)[r * DH + c] = f2bf(o);
            else      ((float*)out)[r * DH + c] = o;
        }
}

extern "C" void kernel_launch(void* const* d_in, const int* in_sizes, int n_in,
                              void* d_out, int out_size, void* d_ws, size_t ws_size,
                              hipStream_t stream) {
    const void* x    = d_in[0];
    const void* rmsk = d_in[1];
    const void* fc_w = d_in[2];
    const void* fc_b = d_in[3];
    const void* w1   = d_in[4];
    const void* w2   = d_in[5];
    const void* b1   = d_in[6];
    const void* wf1  = d_in[7];
    const void* wf2  = d_in[8];
    const void* bfb  = d_in[9];

    float* ws = (float*)d_ws;
    float* rep    = ws;
    float* rep_t  = ws + 1 * 262144;
    float* dep_t  = ws + 2 * 262144;
    float* head_t = ws + 3 * 262144;
    float* attn_t = ws + 4 * 262144;
    int*   flag   = (int*)(ws + 5 * 262144);

    dim3 g(DH / 32, MM / 32), blk(256);
    k_detect<<<1, 64, 0, stream>>>((const unsigned short*)x, (const unsigned short*)fc_w, flag);
    k_fc<<<g, blk, 0, stream>>>(x, fc_w, fc_b, flag, rep, rep_t);
    k_dephead<<<g, blk, 0, stream>>>(rep, w1, w2, b1, flag, dep_t, head_t);
    k_attn<<<dim3(NB * DH), blk, 0, stream>>>(dep_t, head_t, rep_t, attn_t);
    k_fuse<<<g, blk, 0, stream>>>(rep, attn_t, wf1, wf2, bfb, rmsk, flag, (unsigned short*)d_out);
}

// Round 4
// 66.564 us; speedup vs baseline: 1.2332x; 1.2332x over previous
//
#include <hip/hip_runtime.h>
#include <hip/hip_bf16.h>

#define LQ 256
#define NB 4
#define MM 1024   // NB*LQ
#define DH 256
#define CC 5.0f

// ---------------- Kernel A: rep = elu(X @ Wfc^T + b), also write rep_t ----------------
__global__ __launch_bounds__(256) void k_fc(
    const float* __restrict__ X, const float* __restrict__ W, const float* __restrict__ bias,
    float* __restrict__ rep, float* __restrict__ rep_t)
{
    __shared__ float As[32][33];
    __shared__ float Ws[32][33];
    const int tid = threadIdx.x;
    const int bx = blockIdx.x, by = blockIdx.y;
    const int row0 = by * 32, col0 = bx * 32;
    const int lr = tid >> 3, k4 = (tid & 7) * 4;
    const int ty = tid >> 4, tx = tid & 15;
    float a00 = 0.f, a01 = 0.f, a10 = 0.f, a11 = 0.f;
    for (int kk = 0; kk < DH; kk += 32) {
        float4 xa = *(const float4*)(X + (row0 + lr) * DH + kk + k4);
        float4 wa = *(const float4*)(W + (col0 + lr) * DH + kk + k4);
        __syncthreads();
        As[lr][k4 + 0] = xa.x; As[lr][k4 + 1] = xa.y; As[lr][k4 + 2] = xa.z; As[lr][k4 + 3] = xa.w;
        Ws[lr][k4 + 0] = wa.x; Ws[lr][k4 + 1] = wa.y; Ws[lr][k4 + 2] = wa.z; Ws[lr][k4 + 3] = wa.w;
        __syncthreads();
        #pragma unroll
        for (int k = 0; k < 32; ++k) {
            float x0 = As[ty * 2][k], x1 = As[ty * 2 + 1][k];
            float w0 = Ws[tx * 2][k], w1v = Ws[tx * 2 + 1][k];
            a00 += x0 * w0; a01 += x0 * w1v; a10 += x1 * w0; a11 += x1 * w1v;
        }
    }
    float accs[2][2] = {{a00, a01}, {a10, a11}};
    #pragma unroll
    for (int dr = 0; dr < 2; ++dr)
        #pragma unroll
        for (int dc = 0; dc < 2; ++dc) {
            int r = row0 + ty * 2 + dr, c = col0 + tx * 2 + dc;
            float v = accs[dr][dc] + bias[c];
            v = (v > 0.f) ? v : (__expf(v) - 1.f);
            rep[r * DH + c] = v;
            rep_t[((r & 0xFFFFFF00) + c) * LQ + (r & 255)] = v;
        }
}

// ---------------- Kernel B: dep_t = (rep @ W1^T + b1)^T, head_t = (rep @ W2^T)^T ------
__global__ __launch_bounds__(256) void k_dephead(
    const float* __restrict__ rep, const float* __restrict__ W1, const float* __restrict__ W2,
    const float* __restrict__ b1,
    float* __restrict__ dep_t, float* __restrict__ head_t)
{
    __shared__ float As[32][33];
    __shared__ float W1s[32][33];
    __shared__ float W2s[32][33];
    const int tid = threadIdx.x;
    const int bx = blockIdx.x, by = blockIdx.y;
    const int row0 = by * 32, col0 = bx * 32;
    const int lr = tid >> 3, k4 = (tid & 7) * 4;
    const int ty = tid >> 4, tx = tid & 15;
    float d00 = 0.f, d01 = 0.f, d10 = 0.f, d11 = 0.f;
    float h00 = 0.f, h01 = 0.f, h10 = 0.f, h11 = 0.f;
    for (int kk = 0; kk < DH; kk += 32) {
        float4 xa  = *(const float4*)(rep + (row0 + lr) * DH + kk + k4);
        float4 w1a = *(const float4*)(W1  + (col0 + lr) * DH + kk + k4);
        float4 w2a = *(const float4*)(W2  + (col0 + lr) * DH + kk + k4);
        __syncthreads();
        As[lr][k4 + 0] = xa.x; As[lr][k4 + 1] = xa.y; As[lr][k4 + 2] = xa.z; As[lr][k4 + 3] = xa.w;
        W1s[lr][k4 + 0] = w1a.x; W1s[lr][k4 + 1] = w1a.y; W1s[lr][k4 + 2] = w1a.z; W1s[lr][k4 + 3] = w1a.w;
        W2s[lr][k4 + 0] = w2a.x; W2s[lr][k4 + 1] = w2a.y; W2s[lr][k4 + 2] = w2a.z; W2s[lr][k4 + 3] = w2a.w;
        __syncthreads();
        #pragma unroll
        for (int k = 0; k < 32; ++k) {
            float x0 = As[ty * 2][k], x1 = As[ty * 2 + 1][k];
            float u0 = W1s[tx * 2][k], u1 = W1s[tx * 2 + 1][k];
            float v0 = W2s[tx * 2][k], v1 = W2s[tx * 2 + 1][k];
            d00 += x0 * u0; d01 += x0 * u1; d10 += x1 * u0; d11 += x1 * u1;
            h00 += x0 * v0; h01 += x0 * v1; h10 += x1 * v0; h11 += x1 * v1;
        }
    }
    float daccs[2][2] = {{d00, d01}, {d10, d11}};
    float haccs[2][2] = {{h00, h01}, {h10, h11}};
    #pragma unroll
    for (int dr = 0; dr < 2; ++dr)
        #pragma unroll
        for (int dc = 0; dc < 2; ++dc) {
            int r = row0 + ty * 2 + dr, c = col0 + tx * 2 + dc;
            int tix = ((r & 0xFFFFFF00) + c) * LQ + (r & 255);
            dep_t[tix]  = daccs[dr][dc] + b1[c];
            head_t[tix] = haccs[dr][dc];
        }
}

// ---------------- Kernel C: per-(b,h) masked channel-softmax attention (separable exp)
// e_ij = exp(C*tanh((d_j+h_i)/C)) = exp2(A0 + A1*rcp(E_d[j]*E_h[i] + 1))
__global__ __launch_bounds__(64) void k_attn(
    const float* __restrict__ dep_t, const float* __restrict__ head_t,
    const float* __restrict__ rep_t, float* __restrict__ attn_t)
{
    __shared__ float Ed[256];
    __shared__ float Rp[256];
    const int bid = blockIdx.x;
    const int w = bid & 3, bh = bid >> 2;   // interleave heavy/light waves across CUs
    const int lane = threadIdx.x;
    const float k2C = 2.0f / CC;

    {   // stage: 64 threads x 4 j's
        const int j0 = lane * 4;
        float4 d  = *(const float4*)(dep_t + bh * LQ + j0);
        float4 rv = *(const float4*)(rep_t + bh * LQ + j0);
        Ed[j0 + 0] = __expf(k2C * d.x); Ed[j0 + 1] = __expf(k2C * d.y);
        Ed[j0 + 2] = __expf(k2C * d.z); Ed[j0 + 3] = __expf(k2C * d.w);
        Rp[j0 + 0] = rv.x; Rp[j0 + 1] = rv.y; Rp[j0 + 2] = rv.z; Rp[j0 + 3] = rv.w;
    }
    __syncthreads();

    const int i = w * 64 + lane;
    const float Eh = __expf(k2C * head_t[bh * LQ + i]);
    const float A1 = -2.f * CC * 1.44269504f;  // -2C*log2(e)
    const float A0 =  CC * 1.44269504f;        //   C*log2(e)
    float s = 0.f, acc = 0.f;
    const int stop = w * 64;                   // wave-uniform: smallest i in this wave
    for (int jb = 248; jb + 8 > stop; jb -= 8) {
        #pragma unroll
        for (int u = 0; u < 8; ++u) {
            const int j = jb + u;
            float z = Ed[j] * Eh;              // wave-uniform LDS addr -> broadcast
            float r = __builtin_amdgcn_rcpf(z + 1.f);
            float e = __builtin_amdgcn_exp2f(fmaf(A1, r, A0));
            e = (j > i) ? e : 0.f;
            s += e;
            acc = fmaf(e, Rp[j], acc);
        }
    }
    attn_t[bh * LQ + i] = acc / (s + 1e-20f);
}

// ---------------- Kernel D: gate = sigmoid(rep@Wf1^T + attn@Wf2^T + bf); blend -------
__global__ __launch_bounds__(256) void k_fuse(
    const float* __restrict__ rep, const float* __restrict__ attn_t,
    const float* __restrict__ Wf1, const float* __restrict__ Wf2,
    const float* __restrict__ bfb, const float* __restrict__ rmask,
    float* __restrict__ out)
{
    __shared__ float A1s[32][33];
    __shared__ float A2s[32][33];
    __shared__ float W1s[32][33];
    __shared__ float W2s[32][33];
    const int tid = threadIdx.x;
    const int bx = blockIdx.x, by = blockIdx.y;
    const int row0 = by * 32, col0 = bx * 32;
    const int bb = row0 >> 8, i0 = row0 & 255;
    const int lr = tid >> 3, k4 = (tid & 7) * 4;
    const int ty = tid >> 4, tx = tid & 15;
    float a00 = 0.f, a01 = 0.f, a10 = 0.f, a11 = 0.f;
    for (int kk = 0; kk < DH; kk += 32) {
        float4 x1 = *(const float4*)(rep + (row0 + lr) * DH + kk + k4);
        // A2s[l_local][k_local] = attn_t[bb][h=kk+k_local][token=i0+l_local]
        float4 x2 = *(const float4*)(attn_t + (bb * 256 + kk + lr) * LQ + i0 + k4);
        float4 w1a = *(const float4*)(Wf1 + (col0 + lr) * DH + kk + k4);
        float4 w2a = *(const float4*)(Wf2 + (col0 + lr) * DH + kk + k4);
        __syncthreads();
        A1s[lr][k4 + 0] = x1.x; A1s[lr][k4 + 1] = x1.y; A1s[lr][k4 + 2] = x1.z; A1s[lr][k4 + 3] = x1.w;
        A2s[k4 + 0][lr] = x2.x; A2s[k4 + 1][lr] = x2.y; A2s[k4 + 2][lr] = x2.z; A2s[k4 + 3][lr] = x2.w;
        W1s[lr][k4 + 0] = w1a.x; W1s[lr][k4 + 1] = w1a.y; W1s[lr][k4 + 2] = w1a.z; W1s[lr][k4 + 3] = w1a.w;
        W2s[lr][k4 + 0] = w2a.x; W2s[lr][k4 + 1] = w2a.y; W2s[lr][k4 + 2] = w2a.z; W2s[lr][k4 + 3] = w2a.w;
        __syncthreads();
        #pragma unroll
        for (int k = 0; k < 32; ++k) {
            float r0 = A1s[ty * 2][k], r1 = A1s[ty * 2 + 1][k];
            float t0 = A2s[ty * 2][k], t1 = A2s[ty * 2 + 1][k];
            float u0 = W1s[tx * 2][k], u1 = W1s[tx * 2 + 1][k];
            float v0 = W2s[tx * 2][k], v1 = W2s[tx * 2 + 1][k];
            a00 += r0 * u0 + t0 * v0; a01 += r0 * u1 + t0 * v1;
            a10 += r1 * u0 + t1 * v0; a11 += r1 * u1 + t1 * v1;
        }
    }
    float accs[2][2] = {{a00, a01}, {a10, a11}};
    #pragma unroll
    for (int dr = 0; dr < 2; ++dr)
        #pragma unroll
        for (int dc = 0; dc < 2; ++dc) {
            int r = row0 + ty * 2 + dr, c = col0 + tx * 2 + dc;
            float z = accs[dr][dc] + bfb[c];
            float g = 1.f / (1.f + __expf(-z));
            float rv = rep[r * DH + c];
            float av = attn_t[((r & 0xFFFFFF00) + c) * LQ + (r & 255)];
            out[r * DH + c] = (g * rv + (1.f - g) * av) * rmask[r];
        }
}

extern "C" void kernel_launch(void* const* d_in, const int* in_sizes, int n_in,
                              void* d_out, int out_size, void* d_ws, size_t ws_size,
                              hipStream_t stream) {
    const float* x    = (const float*)d_in[0];
    const float* rmsk = (const float*)d_in[1];
    const float* fc_w = (const float*)d_in[2];
    const float* fc_b = (const float*)d_in[3];
    const float* w1   = (const float*)d_in[4];
    const float* w2   = (const float*)d_in[5];
    const float* b1   = (const float*)d_in[6];
    const float* wf1  = (const float*)d_in[7];
    const float* wf2  = (const float*)d_in[8];
    const float* bfb  = (const float*)d_in[9];

    float* ws = (float*)d_ws;
    float* rep    = ws;
    float* rep_t  = ws + 1 * 262144;
    float* dep_t  = ws + 2 * 262144;
    float* head_t = ws + 3 * 262144;
    float* attn_t = ws + 4 * 262144;

    dim3 g(DH / 32, MM / 32), blk(256);
    k_fc<<<g, blk, 0, stream>>>(x, fc_w, fc_b, rep, rep_t);
    k_dephead<<<g, blk, 0, stream>>>(rep, w1, w2, b1, dep_t, head_t);
    k_attn<<<dim3(4096), dim3(64), 0, stream>>>(dep_t, head_t, rep_t, attn_t);
    k_fuse<<<g, blk, 0, stream>>>(rep, attn_t, wf1, wf2, bfb, rmsk, (float*)d_out);
}